// Round 7
// baseline (437.098 us; speedup 1.0000x reference)
//
#include <hip/hip_runtime.h>
#include <hip/hip_bf16.h>
#include <stdint.h>

#define B_ 4
#define T_ 256
#define U_ 128
#define EH_ 1024
#define PH_ 640
#define JH_ 640
#define V_ 1024
#define KT_ 20   // JH / 32 K-tiles

typedef short bf16x8 __attribute__((ext_vector_type(8)));
typedef float f32x4 __attribute__((ext_vector_type(4)));
typedef unsigned short u16;

__device__ __forceinline__ u16 f2bf(float f) {
  union { float f; uint32_t u; } v;
  v.f = f;
  uint32_t u = v.u;
  return (u16)((u + 0x7FFFu + ((u >> 16) & 1u)) >> 16);
}

// HW packed fp32->bf16 (RNE), lo = src0
__device__ __forceinline__ uint32_t cvt2(float lo, float hi) {
  uint32_t r;
  asm("v_cvt_pk_bf16_f32 %0, %1, %2" : "=v"(r) : "v"(lo), "v"(hi));
  return r;
}

// ---------------------------------------------------------------------------
// Transpose + fp32->bf16: in [batch][H][W] -> out [batch][W][H]
// ---------------------------------------------------------------------------
__global__ void k_transpose_cvt(const float* __restrict__ in, u16* __restrict__ out,
                                int H, int W) {
  __shared__ float tile[32][33];
  int b = blockIdx.z;
  int h0 = blockIdx.y * 32, w0 = blockIdx.x * 32;
  const float* pin = in + (size_t)b * H * W;
  u16* pout = out + (size_t)b * H * W;
  int lw = threadIdx.x & 31, lh = threadIdx.x >> 5;
#pragma unroll
  for (int i = 0; i < 4; i++) {
    int h = lh + i * 8;
    tile[h][lw] = pin[(size_t)(h0 + h) * W + (w0 + lw)];
  }
  __syncthreads();
#pragma unroll
  for (int i = 0; i < 4; i++) {
    int w = lh + i * 8;
    pout[(size_t)(w0 + w) * H + (h0 + lw)] = f2bf(tile[lw][w]);
  }
}

// ---------------------------------------------------------------------------
// Merged weight prep: cvt W_enc, cvt W_pred, pack W_out (one launch)
// Wpk u16-index = ((t*4 + g)*1024 + c)*8 + j  ==  W_out[c][t*32 + g*8 + j]
// ---------------------------------------------------------------------------
__global__ void k_prep_w(const float* __restrict__ We, const float* __restrict__ Wp,
                         const float* __restrict__ Wo,
                         u16* __restrict__ WeB, u16* __restrict__ WpB,
                         u16* __restrict__ Wpk) {
  int s = blockIdx.x * 256 + threadIdx.x;
  if (s < 163840) {                       // W_enc: 655360 elems / 4
    int idx = s * 4;
    float4 v = *(const float4*)(We + idx);
    ushort4 o;
    o.x = f2bf(v.x); o.y = f2bf(v.y); o.z = f2bf(v.z); o.w = f2bf(v.w);
    *(ushort4*)(WeB + idx) = o;
  } else if (s < 266240) {                // W_pred: 409600 / 4
    int idx = (s - 163840) * 4;
    float4 v = *(const float4*)(Wp + idx);
    ushort4 o;
    o.x = f2bf(v.x); o.y = f2bf(v.y); o.z = f2bf(v.z); o.w = f2bf(v.w);
    *(ushort4*)(WpB + idx) = o;
  } else {                                // pack W_out: 81920 slots
    int q = s - 266240;
    int c = q & 1023;
    int g = (q >> 10) & 3;
    int t = q >> 12;
    const float* src = Wo + (size_t)c * JH_ + t * 32 + g * 8;
    float4 a = *(const float4*)src;
    float4 b2 = *(const float4*)(src + 4);
    ushort4 lo, hi;
    lo.x = f2bf(a.x);  lo.y = f2bf(a.y);  lo.z = f2bf(a.z);  lo.w = f2bf(a.w);
    hi.x = f2bf(b2.x); hi.y = f2bf(b2.y); hi.z = f2bf(b2.z); hi.w = f2bf(b2.w);
    u16* d = Wpk + (size_t)q * 8;
    *(ushort4*)d = lo;
    *(ushort4*)(d + 4) = hi;
  }
}

// ---------------------------------------------------------------------------
// Projection GEMM: C[m][n] = sum_k A[m][k]*Bm[n][k] + bias[n]
// ---------------------------------------------------------------------------
__global__ void k_proj_gemm(const u16* __restrict__ A, const u16* __restrict__ Bm,
                            const float* __restrict__ bias, float* __restrict__ C,
                            int K, int N, size_t strideA, size_t strideC) {
  __shared__ __align__(16) u16 sA[64 * 64];
  __shared__ __align__(16) u16 sB[64 * 64];
  int bb = blockIdx.z;
  const u16* Ab = A + (size_t)bb * strideA;
  float* Cb = C + (size_t)bb * strideC;
  int m0 = blockIdx.x * 64, n0 = blockIdx.y * 64;
  int tid = threadIdx.x;
  int lane = tid & 63, wid = tid >> 6;

  f32x4 acc[2][2] = {};
  for (int kk = 0; kk < K; kk += 64) {
#pragma unroll
    for (int i = 0; i < 2; i++) {
      int c = tid + i * 256;
      int r = c >> 3, kc = c & 7;
      int s = (r << 3) | (kc ^ (r & 7));
      *(bf16x8*)(sA + s * 8) = *(const bf16x8*)(Ab + (size_t)(m0 + r) * K + kk + kc * 8);
      *(bf16x8*)(sB + s * 8) = *(const bf16x8*)(Bm + (size_t)(n0 + r) * K + kk + kc * 8);
    }
    __syncthreads();
    int wr = (wid >> 1) * 32, wc = (wid & 1) * 32;
    int lr = lane & 15, lk = lane >> 4;
#pragma unroll
    for (int ki = 0; ki < 2; ki++) {
      bf16x8 af[2], bq[2];
#pragma unroll
      for (int mf = 0; mf < 2; mf++) {
        int r = wr + mf * 16 + lr;
        int kc = ki * 4 + lk;
        int s = (r << 3) | (kc ^ (r & 7));
        af[mf] = *(const bf16x8*)(sA + s * 8);
      }
#pragma unroll
      for (int nf = 0; nf < 2; nf++) {
        int r = wc + nf * 16 + lr;
        int kc = ki * 4 + lk;
        int s = (r << 3) | (kc ^ (r & 7));
        bq[nf] = *(const bf16x8*)(sB + s * 8);
      }
#pragma unroll
      for (int mf = 0; mf < 2; mf++)
#pragma unroll
        for (int nf = 0; nf < 2; nf++)
          acc[mf][nf] = __builtin_amdgcn_mfma_f32_16x16x32_bf16(af[mf], bq[nf], acc[mf][nf], 0, 0, 0);
    }
    __syncthreads();
  }
  int wr = (wid >> 1) * 32, wc = (wid & 1) * 32;
  int lr = lane & 15, lq = lane >> 4;
#pragma unroll
  for (int nf = 0; nf < 2; nf++) {
    int n = n0 + wc + nf * 16 + lr;
    float bv = bias[n];
#pragma unroll
    for (int mf = 0; mf < 2; mf++) {
#pragma unroll
      for (int r = 0; r < 4; r++) {
        int m = m0 + wr + mf * 16 + lq * 4 + r;
        Cb[(size_t)m * N + n] = acc[mf][nf][r] + bv;
      }
    }
  }
}

// ---------------------------------------------------------------------------
// Pack p (fp32 [B][128][JH]) into k-major [B][80][128][8] for coalesced
// per-lane 32B loads in k_fused_reg.
// ---------------------------------------------------------------------------
__global__ void k_pack_p(const float* __restrict__ pBuf, float* __restrict__ pPk) {
  int s = blockIdx.x * 256 + threadIdx.x;   // 40960 = 4*80*128
  int m = s & 127;
  int g = (s >> 7) % 80;
  int b = (s >> 7) / 80;
  const float* src = pBuf + ((size_t)b * 128 + m) * JH_ + g * 8;
  float4 a = *(const float4*)src;
  float4 c = *(const float4*)(src + 4);
  float* d = pPk + (size_t)s * 8;
  *(float4*)d = a;
  *(float4*)(d + 4) = c;
}

// ---------------------------------------------------------------------------
// Fused joint GEMM + bias + log_softmax — all-register, barrier-free:
//   out[m][v] = log_softmax_v( relu(e[bt,:]+p[b,u,:]) . W_out[v,:] + b_out[v] )
// Block: 64 M-rows x full V=1024. 512 thr = 8 waves; wave wn owns cols
// [wn*128, wn*128+128). Per tile (BK=32), per lane: B frags direct from Wpk
// (8 x 16B, 256B segments), A frags built in regs from pPk (4 x 32B) + e row
// (32B, L1-broadcast) via v_cvt_pk_bf16_f32. No LDS in main loop -> no
// barriers, no vmcnt discipline; compiler software-pipelines the full unroll.
// s_barrier every 2 tiles only to bound wave skew (p/B L1/L2 locality).
// ---------------------------------------------------------------------------
__global__ __launch_bounds__(512, 2)
void k_fused_reg(const float* __restrict__ e, const float* __restrict__ pPk,
                 const u16* __restrict__ Wpk, const float* __restrict__ bout,
                 float* __restrict__ out) {
  __shared__ float redm[512];
  __shared__ float reds[512];

  int bid = blockIdx.x;
  int btile = bid >> 1, half = bid & 1, b = btile >> 8;
  int tid = threadIdx.x, lane = tid & 63, wn = tid >> 6;
  int lr = lane & 15, lk = lane >> 4;

  const float* eRow = e + (size_t)btile * JH_;
  // pPk: [b][80][128][8]; this block's rows start at half*64
  const float* pB0 = pPk + (((size_t)b * 80 * 128) + half * 64 + lr) * 8;
  const u16* wB0 = Wpk + ((size_t)wn * 128 + lr) * 8;
  float* outB = out + ((size_t)btile * U_ + half * 64) * V_;

  f32x4 acc[4][8] = {};
  float4 pv[4][2];
  float4 ev[2];
  bf16x8 af[4];
  bf16x8 bq[2][8];

  auto loadE = [&](int t) {
    const float* ep = eRow + t * 32 + lk * 8;
    ev[0] = *(const float4*)ep;
    ev[1] = *(const float4*)(ep + 4);
  };
  auto loadP = [&](int t) {
#pragma unroll
    for (int mf = 0; mf < 4; mf++) {
      const float* pp = pB0 + ((size_t)(t * 4 + lk) * 128 + mf * 16) * 8;
      pv[mf][0] = *(const float4*)pp;
      pv[mf][1] = *(const float4*)(pp + 4);
    }
  };
  auto loadB = [&](int t, bf16x8* d) {
#pragma unroll
    for (int nf = 0; nf < 8; nf++)
      d[nf] = *(const bf16x8*)(wB0 + ((size_t)(t * 4 + lk) * 1024 + nf * 16) * 8);
  };
  auto buildA = [&]() {
#pragma unroll
    for (int mf = 0; mf < 4; mf++) {
      union { uint32_t u[4]; bf16x8 v; } r;
      r.u[0] = cvt2(fmaxf(pv[mf][0].x + ev[0].x, 0.f), fmaxf(pv[mf][0].y + ev[0].y, 0.f));
      r.u[1] = cvt2(fmaxf(pv[mf][0].z + ev[0].z, 0.f), fmaxf(pv[mf][0].w + ev[0].w, 0.f));
      r.u[2] = cvt2(fmaxf(pv[mf][1].x + ev[1].x, 0.f), fmaxf(pv[mf][1].y + ev[1].y, 0.f));
      r.u[3] = cvt2(fmaxf(pv[mf][1].z + ev[1].z, 0.f), fmaxf(pv[mf][1].w + ev[1].w, 0.f));
      af[mf] = r.v;
    }
  };

  // prologue: tile 0 fragments
  loadE(0);
  loadP(0);
  loadB(0, bq[0]);
  buildA();

#pragma unroll
  for (int t = 0; t < KT_; t++) {
    const int c = t & 1;
    if (t + 1 < KT_) {
      loadP(t + 1);
      loadE(t + 1);
      loadB(t + 1, bq[c ^ 1]);
    }
#pragma unroll
    for (int mf = 0; mf < 4; mf++)
#pragma unroll
      for (int nf = 0; nf < 8; nf++)
        acc[mf][nf] = __builtin_amdgcn_mfma_f32_16x16x32_bf16(af[mf], bq[c][nf], acc[mf][nf], 0, 0, 0);
    if (t + 1 < KT_) buildA();
    if ((t & 1) == 1 && t + 1 < KT_) __builtin_amdgcn_s_barrier();
  }

  // ---------------- epilogue: bias + log_softmax + fp32 store ----------------
  float bv[8];
#pragma unroll
  for (int nf = 0; nf < 8; nf++) bv[nf] = bout[wn * 128 + nf * 16 + lr];
#pragma unroll
  for (int mf = 0; mf < 4; mf++)
#pragma unroll
    for (int nf = 0; nf < 8; nf++)
#pragma unroll
      for (int r = 0; r < 4; r++)
        acc[mf][nf][r] += bv[nf];

  float gm[4][4];
#pragma unroll
  for (int mf = 0; mf < 4; mf++)
#pragma unroll
    for (int r = 0; r < 4; r++) {
      float m = acc[mf][0][r];
#pragma unroll
      for (int nf = 1; nf < 8; nf++) m = fmaxf(m, acc[mf][nf][r]);
#pragma unroll
      for (int o = 1; o < 16; o <<= 1) m = fmaxf(m, __shfl_xor(m, o, 64));
      gm[mf][r] = m;
    }
  if ((lane & 15) == 0) {
#pragma unroll
    for (int mf = 0; mf < 4; mf++)
#pragma unroll
      for (int r = 0; r < 4; r++)
        redm[(mf * 16 + lk * 4 + r) * 8 + wn] = gm[mf][r];
  }
  __syncthreads();
#pragma unroll
  for (int mf = 0; mf < 4; mf++)
#pragma unroll
    for (int r = 0; r < 4; r++) {
      int row = mf * 16 + lk * 4 + r;
      float m = redm[row * 8];
#pragma unroll
      for (int w = 1; w < 8; w++) m = fmaxf(m, redm[row * 8 + w]);
      gm[mf][r] = m;
    }
  float ls[4][4];
#pragma unroll
  for (int mf = 0; mf < 4; mf++)
#pragma unroll
    for (int r = 0; r < 4; r++) {
      float s = 0.f;
#pragma unroll
      for (int nf = 0; nf < 8; nf++) s += __expf(acc[mf][nf][r] - gm[mf][r]);
#pragma unroll
      for (int o = 1; o < 16; o <<= 1) s += __shfl_xor(s, o, 64);
      ls[mf][r] = s;
    }
  if ((lane & 15) == 0) {
#pragma unroll
    for (int mf = 0; mf < 4; mf++)
#pragma unroll
      for (int r = 0; r < 4; r++)
        reds[(mf * 16 + lk * 4 + r) * 8 + wn] = ls[mf][r];
  }
  __syncthreads();
#pragma unroll
  for (int mf = 0; mf < 4; mf++)
#pragma unroll
    for (int r = 0; r < 4; r++) {
      int row = mf * 16 + lk * 4 + r;
      float s = reds[row * 8];
#pragma unroll
      for (int w = 1; w < 8; w++) s += reds[row * 8 + w];
      ls[mf][r] = gm[mf][r] + __logf(s);
    }
#pragma unroll
  for (int mf = 0; mf < 4; mf++)
#pragma unroll
    for (int nf = 0; nf < 8; nf++)
#pragma unroll
      for (int r = 0; r < 4; r++)
        outB[(size_t)(mf * 16 + lk * 4 + r) * V_ + wn * 128 + nf * 16 + lr] =
            acc[mf][nf][r] - ls[mf][r];
}

// ---------------------------------------------------------------------------
extern "C" void kernel_launch(void* const* d_in, const int* in_sizes, int n_in,
                              void* d_out, int out_size, void* d_ws, size_t ws_size,
                              hipStream_t stream) {
  const float* enc    = (const float*)d_in[0];
  const float* dec    = (const float*)d_in[1];
  const float* W_enc  = (const float*)d_in[2];
  const float* b_enc  = (const float*)d_in[3];
  const float* W_pred = (const float*)d_in[4];
  const float* b_pred = (const float*)d_in[5];
  const float* W_out  = (const float*)d_in[6];
  const float* b_out  = (const float*)d_in[7];
  float* out = (float*)d_out;

  char* ws = (char*)d_ws;
  size_t off = 0;
  auto alloc = [&](size_t bytes) {
    void* pp = ws + off;
    off = (off + bytes + 255) & ~(size_t)255;
    return pp;
  };
  u16* encT   = (u16*)alloc((size_t)B_ * T_ * EH_ * 2);
  u16* decT   = (u16*)alloc((size_t)B_ * U_ * PH_ * 2);
  u16* WencB  = (u16*)alloc((size_t)JH_ * EH_ * 2);
  u16* WpredB = (u16*)alloc((size_t)JH_ * PH_ * 2);
  u16* Wpk    = (u16*)alloc((size_t)KT_ * 32768 * 2);
  float* eBuf = (float*)alloc((size_t)B_ * T_ * JH_ * 4);
  float* pBuf = (float*)alloc((size_t)B_ * U_ * JH_ * 4);
  float* pPk  = (float*)alloc((size_t)B_ * 80 * 128 * 8 * 4);

  // front-end
  k_transpose_cvt<<<dim3(T_ / 32, EH_ / 32, B_), 256, 0, stream>>>(enc, encT, EH_, T_);
  k_transpose_cvt<<<dim3(U_ / 32, PH_ / 32, B_), 256, 0, stream>>>(dec, decT, PH_, U_);
  k_prep_w<<<1360, 256, 0, stream>>>(W_enc, W_pred, W_out, WencB, WpredB, Wpk);
  k_proj_gemm<<<dim3(T_ / 64, JH_ / 64, B_), 256, 0, stream>>>(
      encT, WencB, b_enc, eBuf, EH_, JH_, (size_t)T_ * EH_, (size_t)T_ * JH_);
  k_proj_gemm<<<dim3(U_ / 64, JH_ / 64, B_), 256, 0, stream>>>(
      decT, WpredB, b_pred, pBuf, PH_, JH_, (size_t)U_ * PH_, (size_t)U_ * JH_);
  k_pack_p<<<160, 256, 0, stream>>>(pBuf, pPk);

  // fused joint GEMM + log_softmax: one block per 64 output rows
  k_fused_reg<<<B_ * T_ * 2, 512, 0, stream>>>(eBuf, pPk, Wpk, b_out, out);
}

// Round 8
// 312.721 us; speedup vs baseline: 1.3977x; 1.3977x over previous
//
#include <hip/hip_runtime.h>
#include <hip/hip_bf16.h>
#include <stdint.h>

#define B_ 4
#define T_ 256
#define U_ 128
#define EH_ 1024
#define PH_ 640
#define JH_ 640
#define V_ 1024
#define KT_ 20   // JH / 32 K-tiles

typedef short bf16x8 __attribute__((ext_vector_type(8)));
typedef float f32x4 __attribute__((ext_vector_type(4)));
typedef unsigned short u16;

typedef const __attribute__((address_space(1))) uint32_t cgu32_t;
typedef __attribute__((address_space(3))) uint32_t lu32_t;

__device__ __forceinline__ u16 f2bf(float f) {
  union { float f; uint32_t u; } v;
  v.f = f;
  uint32_t u = v.u;
  return (u16)((u + 0x7FFFu + ((u >> 16) & 1u)) >> 16);
}

// HW packed fp32->bf16 (RNE), lo = src0
__device__ __forceinline__ uint32_t cvt2(float lo, float hi) {
  uint32_t r;
  asm("v_cvt_pk_bf16_f32 %0, %1, %2" : "=v"(r) : "v"(lo), "v"(hi));
  return r;
}

__device__ __forceinline__ void gload16(const void* g, void* l) {
  __builtin_amdgcn_global_load_lds((cgu32_t*)g, (lu32_t*)l, 16, 0, 0);
}

#define VMW(n) asm volatile("s_waitcnt vmcnt(" #n ")" ::: "memory")
#define LGKM0  asm volatile("s_waitcnt lgkmcnt(0)" ::: "memory")
#define SCHEDB __builtin_amdgcn_sched_barrier(0)

// ---------------------------------------------------------------------------
// Transpose + fp32->bf16: in [batch][H][W] -> out [batch][W][H]
// ---------------------------------------------------------------------------
__global__ void k_transpose_cvt(const float* __restrict__ in, u16* __restrict__ out,
                                int H, int W) {
  __shared__ float tile[32][33];
  int b = blockIdx.z;
  int h0 = blockIdx.y * 32, w0 = blockIdx.x * 32;
  const float* pin = in + (size_t)b * H * W;
  u16* pout = out + (size_t)b * H * W;
  int lw = threadIdx.x & 31, lh = threadIdx.x >> 5;
#pragma unroll
  for (int i = 0; i < 4; i++) {
    int h = lh + i * 8;
    tile[h][lw] = pin[(size_t)(h0 + h) * W + (w0 + lw)];
  }
  __syncthreads();
#pragma unroll
  for (int i = 0; i < 4; i++) {
    int w = lh + i * 8;
    pout[(size_t)(w0 + w) * H + (h0 + lw)] = f2bf(tile[lw][w]);
  }
}

// ---------------------------------------------------------------------------
// Merged weight prep: cvt W_enc, cvt W_pred, pack W_out (one launch)
// Wpk u16-index = ((t*4 + g)*1024 + c)*8 + j  ==  W_out[c][t*32 + g*8 + j]
// ---------------------------------------------------------------------------
__global__ void k_prep_w(const float* __restrict__ We, const float* __restrict__ Wp,
                         const float* __restrict__ Wo,
                         u16* __restrict__ WeB, u16* __restrict__ WpB,
                         u16* __restrict__ Wpk) {
  int s = blockIdx.x * 256 + threadIdx.x;
  if (s < 163840) {                       // W_enc: 655360 elems / 4
    int idx = s * 4;
    float4 v = *(const float4*)(We + idx);
    ushort4 o;
    o.x = f2bf(v.x); o.y = f2bf(v.y); o.z = f2bf(v.z); o.w = f2bf(v.w);
    *(ushort4*)(WeB + idx) = o;
  } else if (s < 266240) {                // W_pred: 409600 / 4
    int idx = (s - 163840) * 4;
    float4 v = *(const float4*)(Wp + idx);
    ushort4 o;
    o.x = f2bf(v.x); o.y = f2bf(v.y); o.z = f2bf(v.z); o.w = f2bf(v.w);
    *(ushort4*)(WpB + idx) = o;
  } else {                                // pack W_out: 81920 slots
    int q = s - 266240;
    int c = q & 1023;
    int g = (q >> 10) & 3;
    int t = q >> 12;
    const float* src = Wo + (size_t)c * JH_ + t * 32 + g * 8;
    float4 a = *(const float4*)src;
    float4 b2 = *(const float4*)(src + 4);
    ushort4 lo, hi;
    lo.x = f2bf(a.x);  lo.y = f2bf(a.y);  lo.z = f2bf(a.z);  lo.w = f2bf(a.w);
    hi.x = f2bf(b2.x); hi.y = f2bf(b2.y); hi.z = f2bf(b2.z); hi.w = f2bf(b2.w);
    u16* d = Wpk + (size_t)q * 8;
    *(ushort4*)d = lo;
    *(ushort4*)(d + 4) = hi;
  }
}

// ---------------------------------------------------------------------------
// Projection GEMM: C[m][n] = sum_k A[m][k]*Bm[n][k] + bias[n]
// ---------------------------------------------------------------------------
__global__ void k_proj_gemm(const u16* __restrict__ A, const u16* __restrict__ Bm,
                            const float* __restrict__ bias, float* __restrict__ C,
                            int K, int N, size_t strideA, size_t strideC) {
  __shared__ __align__(16) u16 sA[64 * 64];
  __shared__ __align__(16) u16 sB[64 * 64];
  int bb = blockIdx.z;
  const u16* Ab = A + (size_t)bb * strideA;
  float* Cb = C + (size_t)bb * strideC;
  int m0 = blockIdx.x * 64, n0 = blockIdx.y * 64;
  int tid = threadIdx.x;
  int lane = tid & 63, wid = tid >> 6;

  f32x4 acc[2][2] = {};
  for (int kk = 0; kk < K; kk += 64) {
#pragma unroll
    for (int i = 0; i < 2; i++) {
      int c = tid + i * 256;
      int r = c >> 3, kc = c & 7;
      int s = (r << 3) | (kc ^ (r & 7));
      *(bf16x8*)(sA + s * 8) = *(const bf16x8*)(Ab + (size_t)(m0 + r) * K + kk + kc * 8);
      *(bf16x8*)(sB + s * 8) = *(const bf16x8*)(Bm + (size_t)(n0 + r) * K + kk + kc * 8);
    }
    __syncthreads();
    int wr = (wid >> 1) * 32, wc = (wid & 1) * 32;
    int lr = lane & 15, lk = lane >> 4;
#pragma unroll
    for (int ki = 0; ki < 2; ki++) {
      bf16x8 af[2], bq[2];
#pragma unroll
      for (int mf = 0; mf < 2; mf++) {
        int r = wr + mf * 16 + lr;
        int kc = ki * 4 + lk;
        int s = (r << 3) | (kc ^ (r & 7));
        af[mf] = *(const bf16x8*)(sA + s * 8);
      }
#pragma unroll
      for (int nf = 0; nf < 2; nf++) {
        int r = wc + nf * 16 + lr;
        int kc = ki * 4 + lk;
        int s = (r << 3) | (kc ^ (r & 7));
        bq[nf] = *(const bf16x8*)(sB + s * 8);
      }
#pragma unroll
      for (int mf = 0; mf < 2; mf++)
#pragma unroll
        for (int nf = 0; nf < 2; nf++)
          acc[mf][nf] = __builtin_amdgcn_mfma_f32_16x16x32_bf16(af[mf], bq[nf], acc[mf][nf], 0, 0, 0);
    }
    __syncthreads();
  }
  int wr = (wid >> 1) * 32, wc = (wid & 1) * 32;
  int lr = lane & 15, lq = lane >> 4;
#pragma unroll
  for (int nf = 0; nf < 2; nf++) {
    int n = n0 + wc + nf * 16 + lr;
    float bv = bias[n];
#pragma unroll
    for (int mf = 0; mf < 2; mf++) {
#pragma unroll
      for (int r = 0; r < 4; r++) {
        int m = m0 + wr + mf * 16 + lq * 4 + r;
        Cb[(size_t)m * N + n] = acc[mf][nf][r] + bv;
      }
    }
  }
}

// ---------------------------------------------------------------------------
// Pack p (fp32 [B][128][JH]) into [b*2+half][160 g4][64 rows][4] floats so
// k_fused3's per-(wave,tile) float4 p-loads are perfectly coalesced.
// ---------------------------------------------------------------------------
__global__ void k_pack_p2(const float* __restrict__ pBuf, float* __restrict__ pPk) {
  int s = blockIdx.x * 256 + threadIdx.x;   // 81920 float4 slots
  int bh = s / 10240;
  int rem = s - bh * 10240;
  int g4 = rem >> 6;
  int r = rem & 63;
  int b = bh >> 1, half = bh & 1;
  const float* src = pBuf + ((size_t)(b * 128 + half * 64 + r)) * JH_ + g4 * 4;
  float4 v = *(const float4*)src;
  *(float4*)(pPk + (size_t)s * 4) = v;
}

// ---------------------------------------------------------------------------
// Fused joint GEMM + bias + log_softmax, chunked-A / barrier-free-B pipeline:
//   out[m][v] = log_softmax_v( relu(e[bt,:]+p[b,u,:]) . W_out[v,:] + b_out[v] )
// 64 rows x V=1024 per block; 512 thr = 8 waves; wave wn owns cols
// [128wn,128wn+128) AND self-stages exactly those cols (B needs no barrier:
// per-wave vmcnt ledger only). A (cooperative, 2KB/tile) built in 2-tile
// chunks, double-buffered -> ONE barrier per 2 tiles. Per-block K-tile phase
// rotation (ph=2*(bid%10)) de-hotspots the shared Wpk window in L2.
// Ledger: iter t issues stage(t+1)[8] (+2 p-loads on even t); VMW(10) forces
// exactly stage(t) for t<=15; tails VMW(8)@16-18, VMW(0)@19.
// ---------------------------------------------------------------------------
__global__ __launch_bounds__(512)
void k_fused3(const float* __restrict__ e, const float* __restrict__ pPk,
              const u16* __restrict__ Wpk, const float* __restrict__ bout,
              float* __restrict__ out) {
  __shared__ __align__(16) u16 sB[2][32768];   // [buf][g<4][1024 cols][8]
  __shared__ __align__(16) u16 sA[2][4096];    // [chunk][tin<2][koct<4][64 rows][8]
  __shared__ __align__(16) float sE[JH_];
  __shared__ float redm[512];
  __shared__ float reds[512];

  int bid = blockIdx.x;
  int btile = bid >> 1, half = bid & 1, b = btile >> 8;
  int tid = threadIdx.x, lane = tid & 63, wn = tid >> 6;
  int lr = lane & 15, lk = lane >> 4;
  int ph = (bid % 10) * 2;

  const float* eRow = e + (size_t)btile * JH_;
  const float* pPbase = pPk + ((size_t)(b * 2 + half) * 40960) + wn * 256 + lane * 4;
  float* outB = out + ((size_t)btile * U_ + half * 64) * V_;

  // A-build: thread (wn=k-quad, lane=row) writes 4 bf16 at:
  int awr = (wn >> 1) * 512 + lane * 8 + (wn & 1) * 4;

  f32x4 acc[4][8] = {};

  auto tp = [&](int t) { int x = t + ph; return x >= KT_ ? x - KT_ : x; };
  auto stage = [&](int tph, int c) {
    const u16* s0 = Wpk + (size_t)tph * 32768 + (2 * wn) * 512 + lane * 8;
    u16* d0 = &sB[c][(2 * wn) * 512];
#pragma unroll
    for (int g = 0; g < 4; g++) {
      gload16(s0 + g * 8192, d0 + g * 8192);
      gload16(s0 + g * 8192 + 512, d0 + g * 8192 + 512);
    }
  };
  auto loadp = [&](int tph) { return *(const float4*)(pPbase + tph * 2048); };
  auto build = [&](int slot, int tin, int tph, float4 pv) {
    float4 ev = *(const float4*)(&sE[tph * 32 + wn * 4]);
    uint2 w;
    w.x = cvt2(fmaxf(pv.x + ev.x, 0.f), fmaxf(pv.y + ev.y, 0.f));
    w.y = cvt2(fmaxf(pv.z + ev.z, 0.f), fmaxf(pv.w + ev.w, 0.f));
    *(uint2*)(&sA[slot][tin * 2048 + awr]) = w;
  };

  // ---- prologue
  for (int i = tid; i < JH_; i += 512) sE[i] = eRow[i];
  stage(tp(0), 0);
  float4 p0  = loadp(tp(0));
  float4 p1  = loadp(tp(1));
  float4 pcA = loadp(tp(2));
  float4 pcB = loadp(tp(3));
  float4 pnA = p0, pnB = p0;                 // init to silence undef
  LGKM0;
  __builtin_amdgcn_s_barrier();              // sE visible
  build(0, 0, tp(0), p0);
  build(0, 1, tp(1), p1);
  asm volatile("s_waitcnt vmcnt(0) lgkmcnt(0)" ::: "memory");
  __builtin_amdgcn_s_barrier();              // A chunk 0 + B tile 0 ready

#pragma unroll
  for (int t = 0; t < KT_; t++) {
    if (t + 1 < KT_) stage(tp(t + 1), (t + 1) & 1);
    if ((t & 1) == 0 && t + 4 < KT_) { pnA = loadp(tp(t + 4)); pnB = loadp(tp(t + 5)); }
    if ((t & 1) == 0 && t + 2 < KT_) {
      int q1 = ((t >> 1) + 1) & 1;
      build(q1, 0, tp(t + 2), pcA);
      build(q1, 1, tp(t + 3), pcB);
    }
    SCHEDB;
    if (t <= 15) { VMW(10); } else if (t <= 18) { VMW(8); } else { VMW(0); }
    SCHEDB;
    const u16* Ab = &sA[(t >> 1) & 1][(t & 1) * 2048 + lk * 512];
    const u16* Bb = &sB[t & 1][lk * 8192 + wn * 1024];
    bf16x8 af[4], bq[8];
#pragma unroll
    for (int mf = 0; mf < 4; mf++)
      af[mf] = *(const bf16x8*)(Ab + (mf * 16 + lr) * 8);
#pragma unroll
    for (int nf = 0; nf < 8; nf++)
      bq[nf] = *(const bf16x8*)(Bb + (nf * 16 + lr) * 8);
    LGKM0; SCHEDB;
    __builtin_amdgcn_s_setprio(1);
#pragma unroll
    for (int mf = 0; mf < 4; mf++)
#pragma unroll
      for (int nf = 0; nf < 8; nf++)
        acc[mf][nf] = __builtin_amdgcn_mfma_f32_16x16x32_bf16(af[mf], bq[nf], acc[mf][nf], 0, 0, 0);
    __builtin_amdgcn_s_setprio(0);
    if ((t & 1) && t + 1 < KT_) {            // chunk boundary
      pcA = pnA; pcB = pnB;
      LGKM0;                                 // drain A-builds of next chunk
      __builtin_amdgcn_s_barrier();
    }
  }

  // ---------------- epilogue: bias + log_softmax + fp32 store ----------------
  float bv[8];
#pragma unroll
  for (int nf = 0; nf < 8; nf++) bv[nf] = bout[wn * 128 + nf * 16 + lr];
#pragma unroll
  for (int mf = 0; mf < 4; mf++)
#pragma unroll
    for (int nf = 0; nf < 8; nf++)
#pragma unroll
      for (int r = 0; r < 4; r++)
        acc[mf][nf][r] += bv[nf];

  float gm[4][4];
#pragma unroll
  for (int mf = 0; mf < 4; mf++)
#pragma unroll
    for (int r = 0; r < 4; r++) {
      float m = acc[mf][0][r];
#pragma unroll
      for (int nf = 1; nf < 8; nf++) m = fmaxf(m, acc[mf][nf][r]);
#pragma unroll
      for (int o = 1; o < 16; o <<= 1) m = fmaxf(m, __shfl_xor(m, o, 64));
      gm[mf][r] = m;
    }
  if ((lane & 15) == 0) {
#pragma unroll
    for (int mf = 0; mf < 4; mf++)
#pragma unroll
      for (int r = 0; r < 4; r++)
        redm[(mf * 16 + lk * 4 + r) * 8 + wn] = gm[mf][r];
  }
  __syncthreads();
#pragma unroll
  for (int mf = 0; mf < 4; mf++)
#pragma unroll
    for (int r = 0; r < 4; r++) {
      int row = mf * 16 + lk * 4 + r;
      float m = redm[row * 8];
#pragma unroll
      for (int w = 1; w < 8; w++) m = fmaxf(m, redm[row * 8 + w]);
      gm[mf][r] = m;
    }
  float ls[4][4];
#pragma unroll
  for (int mf = 0; mf < 4; mf++)
#pragma unroll
    for (int r = 0; r < 4; r++) {
      float s = 0.f;
#pragma unroll
      for (int nf = 0; nf < 8; nf++) s += __expf(acc[mf][nf][r] - gm[mf][r]);
#pragma unroll
      for (int o = 1; o < 16; o <<= 1) s += __shfl_xor(s, o, 64);
      ls[mf][r] = s;
    }
  if ((lane & 15) == 0) {
#pragma unroll
    for (int mf = 0; mf < 4; mf++)
#pragma unroll
      for (int r = 0; r < 4; r++)
        reds[(mf * 16 + lk * 4 + r) * 8 + wn] = ls[mf][r];
  }
  __syncthreads();
#pragma unroll
  for (int mf = 0; mf < 4; mf++)
#pragma unroll
    for (int r = 0; r < 4; r++) {
      int row = mf * 16 + lk * 4 + r;
      float s = reds[row * 8];
#pragma unroll
      for (int w = 1; w < 8; w++) s += reds[row * 8 + w];
      ls[mf][r] = gm[mf][r] + __logf(s);
    }
#pragma unroll
  for (int mf = 0; mf < 4; mf++)
#pragma unroll
    for (int nf = 0; nf < 8; nf++)
#pragma unroll
      for (int r = 0; r < 4; r++)
        outB[(size_t)(mf * 16 + lk * 4 + r) * V_ + wn * 128 + nf * 16 + lr] =
            acc[mf][nf][r] - ls[mf][r];
}

// ---------------------------------------------------------------------------
extern "C" void kernel_launch(void* const* d_in, const int* in_sizes, int n_in,
                              void* d_out, int out_size, void* d_ws, size_t ws_size,
                              hipStream_t stream) {
  const float* enc    = (const float*)d_in[0];
  const float* dec    = (const float*)d_in[1];
  const float* W_enc  = (const float*)d_in[2];
  const float* b_enc  = (const float*)d_in[3];
  const float* W_pred = (const float*)d_in[4];
  const float* b_pred = (const float*)d_in[5];
  const float* W_out  = (const float*)d_in[6];
  const float* b_out  = (const float*)d_in[7];
  float* out = (float*)d_out;

  char* ws = (char*)d_ws;
  size_t off = 0;
  auto alloc = [&](size_t bytes) {
    void* pp = ws + off;
    off = (off + bytes + 255) & ~(size_t)255;
    return pp;
  };
  u16* encT   = (u16*)alloc((size_t)B_ * T_ * EH_ * 2);
  u16* decT   = (u16*)alloc((size_t)B_ * U_ * PH_ * 2);
  u16* WencB  = (u16*)alloc((size_t)JH_ * EH_ * 2);
  u16* WpredB = (u16*)alloc((size_t)JH_ * PH_ * 2);
  u16* Wpk    = (u16*)alloc((size_t)KT_ * 32768 * 2);
  float* eBuf = (float*)alloc((size_t)B_ * T_ * JH_ * 4);
  float* pBuf = (float*)alloc((size_t)B_ * U_ * JH_ * 4);
  float* pPk  = (float*)alloc((size_t)81920 * 4 * 4);

  // front-end
  k_transpose_cvt<<<dim3(T_ / 32, EH_ / 32, B_), 256, 0, stream>>>(enc, encT, EH_, T_);
  k_transpose_cvt<<<dim3(U_ / 32, PH_ / 32, B_), 256, 0, stream>>>(dec, decT, PH_, U_);
  k_prep_w<<<1360, 256, 0, stream>>>(W_enc, W_pred, W_out, WencB, WpredB, Wpk);
  k_proj_gemm<<<dim3(T_ / 64, JH_ / 64, B_), 256, 0, stream>>>(
      encT, WencB, b_enc, eBuf, EH_, JH_, (size_t)T_ * EH_, (size_t)T_ * JH_);
  k_proj_gemm<<<dim3(U_ / 64, JH_ / 64, B_), 256, 0, stream>>>(
      decT, WpredB, b_pred, pBuf, PH_, JH_, (size_t)U_ * PH_, (size_t)U_ * JH_);
  k_pack_p2<<<320, 256, 0, stream>>>(pBuf, pPk);

  // fused joint GEMM + log_softmax: one block per 64 output rows
  k_fused3<<<B_ * T_ * 2, 512, 0, stream>>>(eBuf, pPk, Wpk, b_out, out);
}

// Round 9
// 298.855 us; speedup vs baseline: 1.4626x; 1.0464x over previous
//
#include <hip/hip_runtime.h>
#include <hip/hip_bf16.h>
#include <stdint.h>

#define B_ 4
#define T_ 256
#define U_ 128
#define EH_ 1024
#define PH_ 640
#define JH_ 640
#define V_ 1024
#define KT_ 20   // JH / 32 K-tiles

typedef short bf16x8 __attribute__((ext_vector_type(8)));
typedef float f32x4 __attribute__((ext_vector_type(4)));
typedef unsigned short u16;

__device__ __forceinline__ u16 f2bf(float f) {
  union { float f; uint32_t u; } v;
  v.f = f;
  uint32_t u = v.u;
  return (u16)((u + 0x7FFFu + ((u >> 16) & 1u)) >> 16);
}

// HW packed fp32->bf16 (RNE), lo = src0
__device__ __forceinline__ uint32_t cvt2(float lo, float hi) {
  uint32_t r;
  asm("v_cvt_pk_bf16_f32 %0, %1, %2" : "=v"(r) : "v"(lo), "v"(hi));
  return r;
}

#define LGKM0  asm volatile("s_waitcnt lgkmcnt(0)" ::: "memory")

// ---------------------------------------------------------------------------
// Transpose + fp32->bf16: in [batch][H][W] -> out [batch][W][H]
// ---------------------------------------------------------------------------
__global__ void k_transpose_cvt(const float* __restrict__ in, u16* __restrict__ out,
                                int H, int W) {
  __shared__ float tile[32][33];
  int b = blockIdx.z;
  int h0 = blockIdx.y * 32, w0 = blockIdx.x * 32;
  const float* pin = in + (size_t)b * H * W;
  u16* pout = out + (size_t)b * H * W;
  int lw = threadIdx.x & 31, lh = threadIdx.x >> 5;
#pragma unroll
  for (int i = 0; i < 4; i++) {
    int h = lh + i * 8;
    tile[h][lw] = pin[(size_t)(h0 + h) * W + (w0 + lw)];
  }
  __syncthreads();
#pragma unroll
  for (int i = 0; i < 4; i++) {
    int w = lh + i * 8;
    pout[(size_t)(w0 + w) * H + (h0 + lw)] = f2bf(tile[lw][w]);
  }
}

// ---------------------------------------------------------------------------
// Merged weight prep: cvt W_enc, cvt W_pred, pack W_out (one launch)
// Wpk u16-index = ((t*4 + g)*1024 + c)*8 + j  ==  W_out[c][t*32 + g*8 + j]
// ---------------------------------------------------------------------------
__global__ void k_prep_w(const float* __restrict__ We, const float* __restrict__ Wp,
                         const float* __restrict__ Wo,
                         u16* __restrict__ WeB, u16* __restrict__ WpB,
                         u16* __restrict__ Wpk) {
  int s = blockIdx.x * 256 + threadIdx.x;
  if (s < 163840) {                       // W_enc: 655360 elems / 4
    int idx = s * 4;
    float4 v = *(const float4*)(We + idx);
    ushort4 o;
    o.x = f2bf(v.x); o.y = f2bf(v.y); o.z = f2bf(v.z); o.w = f2bf(v.w);
    *(ushort4*)(WeB + idx) = o;
  } else if (s < 266240) {                // W_pred: 409600 / 4
    int idx = (s - 163840) * 4;
    float4 v = *(const float4*)(Wp + idx);
    ushort4 o;
    o.x = f2bf(v.x); o.y = f2bf(v.y); o.z = f2bf(v.z); o.w = f2bf(v.w);
    *(ushort4*)(WpB + idx) = o;
  } else {                                // pack W_out: 81920 slots
    int q = s - 266240;
    int c = q & 1023;
    int g = (q >> 10) & 3;
    int t = q >> 12;
    const float* src = Wo + (size_t)c * JH_ + t * 32 + g * 8;
    float4 a = *(const float4*)src;
    float4 b2 = *(const float4*)(src + 4);
    ushort4 lo, hi;
    lo.x = f2bf(a.x);  lo.y = f2bf(a.y);  lo.z = f2bf(a.z);  lo.w = f2bf(a.w);
    hi.x = f2bf(b2.x); hi.y = f2bf(b2.y); hi.z = f2bf(b2.z); hi.w = f2bf(b2.w);
    u16* d = Wpk + (size_t)q * 8;
    *(ushort4*)d = lo;
    *(ushort4*)(d + 4) = hi;
  }
}

// ---------------------------------------------------------------------------
// Projection GEMM: C[m][n] = sum_k A[m][k]*Bm[n][k] + bias[n]
// ---------------------------------------------------------------------------
__global__ void k_proj_gemm(const u16* __restrict__ A, const u16* __restrict__ Bm,
                            const float* __restrict__ bias, float* __restrict__ C,
                            int K, int N, size_t strideA, size_t strideC) {
  __shared__ __align__(16) u16 sA[64 * 64];
  __shared__ __align__(16) u16 sB[64 * 64];
  int bb = blockIdx.z;
  const u16* Ab = A + (size_t)bb * strideA;
  float* Cb = C + (size_t)bb * strideC;
  int m0 = blockIdx.x * 64, n0 = blockIdx.y * 64;
  int tid = threadIdx.x;
  int lane = tid & 63, wid = tid >> 6;

  f32x4 acc[2][2] = {};
  for (int kk = 0; kk < K; kk += 64) {
#pragma unroll
    for (int i = 0; i < 2; i++) {
      int c = tid + i * 256;
      int r = c >> 3, kc = c & 7;
      int s = (r << 3) | (kc ^ (r & 7));
      *(bf16x8*)(sA + s * 8) = *(const bf16x8*)(Ab + (size_t)(m0 + r) * K + kk + kc * 8);
      *(bf16x8*)(sB + s * 8) = *(const bf16x8*)(Bm + (size_t)(n0 + r) * K + kk + kc * 8);
    }
    __syncthreads();
    int wr = (wid >> 1) * 32, wc = (wid & 1) * 32;
    int lr = lane & 15, lk = lane >> 4;
#pragma unroll
    for (int ki = 0; ki < 2; ki++) {
      bf16x8 af[2], bq[2];
#pragma unroll
      for (int mf = 0; mf < 2; mf++) {
        int r = wr + mf * 16 + lr;
        int kc = ki * 4 + lk;
        int s = (r << 3) | (kc ^ (r & 7));
        af[mf] = *(const bf16x8*)(sA + s * 8);
      }
#pragma unroll
      for (int nf = 0; nf < 2; nf++) {
        int r = wc + nf * 16 + lr;
        int kc = ki * 4 + lk;
        int s = (r << 3) | (kc ^ (r & 7));
        bq[nf] = *(const bf16x8*)(sB + s * 8);
      }
#pragma unroll
      for (int mf = 0; mf < 2; mf++)
#pragma unroll
        for (int nf = 0; nf < 2; nf++)
          acc[mf][nf] = __builtin_amdgcn_mfma_f32_16x16x32_bf16(af[mf], bq[nf], acc[mf][nf], 0, 0, 0);
    }
    __syncthreads();
  }
  int wr = (wid >> 1) * 32, wc = (wid & 1) * 32;
  int lr = lane & 15, lq = lane >> 4;
#pragma unroll
  for (int nf = 0; nf < 2; nf++) {
    int n = n0 + wc + nf * 16 + lr;
    float bv = bias[n];
#pragma unroll
    for (int mf = 0; mf < 2; mf++) {
#pragma unroll
      for (int r = 0; r < 4; r++) {
        int m = m0 + wr + mf * 16 + lq * 4 + r;
        Cb[(size_t)m * N + n] = acc[mf][nf][r] + bv;
      }
    }
  }
}

// ---------------------------------------------------------------------------
// Pack p (fp32 [B][128][JH]) into [b*2+half][160 g4][64 rows][4] floats so
// k_fused4's per-(wave,tile) float4 p-loads are perfectly coalesced.
// ---------------------------------------------------------------------------
__global__ void k_pack_p2(const float* __restrict__ pBuf, float* __restrict__ pPk) {
  int s = blockIdx.x * 256 + threadIdx.x;   // 81920 float4 slots
  int bh = s / 10240;
  int rem = s - bh * 10240;
  int g4 = rem >> 6;
  int r = rem & 63;
  int b = bh >> 1, half = bh & 1;
  const float* src = pBuf + ((size_t)(b * 128 + half * 64 + r)) * JH_ + g4 * 4;
  float4 v = *(const float4*)src;
  *(float4*)(pPk + (size_t)s * 4) = v;
}

// ---------------------------------------------------------------------------
// Fused joint GEMM + bias + log_softmax, register-B / chunked-LDS-A:
//   out[m][v] = log_softmax_v( relu(e[bt,:]+p[b,u,:]) . W_out[v,:] + b_out[v] )
// 64 rows x V=1024 per block; 512 thr = 8 waves; wave wn owns cols
// [128wn,128wn+128). B fragments stream DIRECTLY to registers (wave-private
// cols; double-buffered bq[2][8]; loads issued one tile ahead; compiler's
// counted vmcnt covers L2 latency - no hard drains). A (cooperative,
// 2KB/tile) built in LDS in 2-tile chunks from packed p + sE via
// v_cvt_pk_bf16_f32 -> ONE LGKM0+barrier per 2 tiles; that is ALL the sync.
// Per-block K-tile phase rotation de-hotspots the shared Wpk window in L2.
// LDS total ~22.5 KB.
// ---------------------------------------------------------------------------
__global__ __launch_bounds__(512)
void k_fused4(const float* __restrict__ e, const float* __restrict__ pPk,
              const u16* __restrict__ Wpk, const float* __restrict__ bout,
              float* __restrict__ out) {
  __shared__ __align__(16) u16 sA[2][4096];    // [chunk][tin<2][koct<4][64 rows][8]
  __shared__ __align__(16) float sE[JH_];
  __shared__ float redm[512];
  __shared__ float reds[512];

  int bid = blockIdx.x;
  int btile = bid >> 1, half = bid & 1, b = btile >> 8;
  int tid = threadIdx.x, lane = tid & 63, wn = tid >> 6;
  int lr = lane & 15, lk = lane >> 4;
  int ph = (bid % 10) * 2;

  const float* eRow = e + (size_t)btile * JH_;
  const float* pPbase = pPk + ((size_t)(b * 2 + half) * 40960) + wn * 256 + lane * 4;
  const u16* wB = Wpk + ((size_t)lk * 1024 + wn * 128 + lr) * 8;
  float* outB = out + ((size_t)btile * U_ + half * 64) * V_;

  // A-build: thread (wn=k-quad, lane=row) writes 4 bf16 at:
  int awr = (wn >> 1) * 512 + lane * 8 + (wn & 1) * 4;

  f32x4 acc[4][8] = {};
  bf16x8 bq[2][8];

  auto tp = [&](int t) { int x = t + ph; return x >= KT_ ? x - KT_ : x; };
  auto loadB = [&](int tph, bf16x8* d) {
#pragma unroll
    for (int nf = 0; nf < 8; nf++)
      d[nf] = *(const bf16x8*)(wB + (size_t)tph * 32768 + nf * 128);
  };
  auto loadp = [&](int tph) { return *(const float4*)(pPbase + tph * 2048); };
  auto build = [&](int slot, int tin, int tph, float4 pv) {
    float4 ev = *(const float4*)(&sE[tph * 32 + wn * 4]);
    uint2 w;
    w.x = cvt2(fmaxf(pv.x + ev.x, 0.f), fmaxf(pv.y + ev.y, 0.f));
    w.y = cvt2(fmaxf(pv.z + ev.z, 0.f), fmaxf(pv.w + ev.w, 0.f));
    *(uint2*)(&sA[slot][tin * 2048 + awr]) = w;
  };

  // ---- prologue
  loadB(tp(0), bq[0]);                        // earliest possible issue
  for (int i = tid; i < JH_; i += 512) sE[i] = eRow[i];
  float4 p0  = loadp(tp(0));
  float4 p1  = loadp(tp(1));
  float4 pcA = loadp(tp(2));
  float4 pcB = loadp(tp(3));
  float4 pnA = p0, pnB = p0;                  // init to silence undef
  LGKM0;
  __builtin_amdgcn_s_barrier();               // sE visible
  build(0, 0, tp(0), p0);
  build(0, 1, tp(1), p1);
  LGKM0;
  __builtin_amdgcn_s_barrier();               // A chunk 0 visible

#pragma unroll
  for (int t = 0; t < KT_; t++) {
    if (t + 1 < KT_) loadB(tp(t + 1), bq[(t + 1) & 1]);
    if ((t & 1) == 0) {
      if (t + 4 < KT_) { pnA = loadp(tp(t + 4)); pnB = loadp(tp(t + 5)); }
      if (t + 2 < KT_) {
        int q1 = ((t >> 1) + 1) & 1;
        build(q1, 0, tp(t + 2), pcA);
        build(q1, 1, tp(t + 3), pcB);
      }
    }
    const u16* Ab = &sA[(t >> 1) & 1][(t & 1) * 2048 + lk * 512];
    bf16x8 af[4];
#pragma unroll
    for (int mf = 0; mf < 4; mf++)
      af[mf] = *(const bf16x8*)(Ab + (mf * 16 + lr) * 8);
    __builtin_amdgcn_s_setprio(1);
#pragma unroll
    for (int mf = 0; mf < 4; mf++)
#pragma unroll
      for (int nf = 0; nf < 8; nf++)
        acc[mf][nf] = __builtin_amdgcn_mfma_f32_16x16x32_bf16(af[mf], bq[t & 1][nf], acc[mf][nf], 0, 0, 0);
    __builtin_amdgcn_s_setprio(0);
    if ((t & 1) && t + 1 < KT_) {             // chunk boundary
      pcA = pnA; pcB = pnB;
      LGKM0;                                  // drain builds of next chunk
      __builtin_amdgcn_s_barrier();
    }
  }

  // ---------------- epilogue: bias + log_softmax + fp32 store ----------------
  float bv[8];
#pragma unroll
  for (int nf = 0; nf < 8; nf++) bv[nf] = bout[wn * 128 + nf * 16 + lr];
#pragma unroll
  for (int mf = 0; mf < 4; mf++)
#pragma unroll
    for (int nf = 0; nf < 8; nf++)
#pragma unroll
      for (int r = 0; r < 4; r++)
        acc[mf][nf][r] += bv[nf];

  float gm[4][4];
#pragma unroll
  for (int mf = 0; mf < 4; mf++)
#pragma unroll
    for (int r = 0; r < 4; r++) {
      float m = acc[mf][0][r];
#pragma unroll
      for (int nf = 1; nf < 8; nf++) m = fmaxf(m, acc[mf][nf][r]);
#pragma unroll
      for (int o = 1; o < 16; o <<= 1) m = fmaxf(m, __shfl_xor(m, o, 64));
      gm[mf][r] = m;
    }
  if ((lane & 15) == 0) {
#pragma unroll
    for (int mf = 0; mf < 4; mf++)
#pragma unroll
      for (int r = 0; r < 4; r++)
        redm[(mf * 16 + lk * 4 + r) * 8 + wn] = gm[mf][r];
  }
  __syncthreads();
#pragma unroll
  for (int mf = 0; mf < 4; mf++)
#pragma unroll
    for (int r = 0; r < 4; r++) {
      int row = mf * 16 + lk * 4 + r;
      float m = redm[row * 8];
#pragma unroll
      for (int w = 1; w < 8; w++) m = fmaxf(m, redm[row * 8 + w]);
      gm[mf][r] = m;
    }
  float ls[4][4];
#pragma unroll
  for (int mf = 0; mf < 4; mf++)
#pragma unroll
    for (int r = 0; r < 4; r++) {
      float s = 0.f;
#pragma unroll
      for (int nf = 0; nf < 8; nf++) s += __expf(acc[mf][nf][r] - gm[mf][r]);
#pragma unroll
      for (int o = 1; o < 16; o <<= 1) s += __shfl_xor(s, o, 64);
      ls[mf][r] = s;
    }
  if ((lane & 15) == 0) {
#pragma unroll
    for (int mf = 0; mf < 4; mf++)
#pragma unroll
      for (int r = 0; r < 4; r++)
        reds[(mf * 16 + lk * 4 + r) * 8 + wn] = ls[mf][r];
  }
  __syncthreads();
#pragma unroll
  for (int mf = 0; mf < 4; mf++)
#pragma unroll
    for (int r = 0; r < 4; r++) {
      int row = mf * 16 + lk * 4 + r;
      float s = reds[row * 8];
#pragma unroll
      for (int w = 1; w < 8; w++) s += reds[row * 8 + w];
      ls[mf][r] = gm[mf][r] + __logf(s);
    }
#pragma unroll
  for (int mf = 0; mf < 4; mf++)
#pragma unroll
    for (int nf = 0; nf < 8; nf++)
#pragma unroll
      for (int r = 0; r < 4; r++)
        outB[(size_t)(mf * 16 + lk * 4 + r) * V_ + wn * 128 + nf * 16 + lr] =
            acc[mf][nf][r] - ls[mf][r];
}

// ---------------------------------------------------------------------------
extern "C" void kernel_launch(void* const* d_in, const int* in_sizes, int n_in,
                              void* d_out, int out_size, void* d_ws, size_t ws_size,
                              hipStream_t stream) {
  const float* enc    = (const float*)d_in[0];
  const float* dec    = (const float*)d_in[1];
  const float* W_enc  = (const float*)d_in[2];
  const float* b_enc  = (const float*)d_in[3];
  const float* W_pred = (const float*)d_in[4];
  const float* b_pred = (const float*)d_in[5];
  const float* W_out  = (const float*)d_in[6];
  const float* b_out  = (const float*)d_in[7];
  float* out = (float*)d_out;

  char* ws = (char*)d_ws;
  size_t off = 0;
  auto alloc = [&](size_t bytes) {
    void* pp = ws + off;
    off = (off + bytes + 255) & ~(size_t)255;
    return pp;
  };
  u16* encT   = (u16*)alloc((size_t)B_ * T_ * EH_ * 2);
  u16* decT   = (u16*)alloc((size_t)B_ * U_ * PH_ * 2);
  u16* WencB  = (u16*)alloc((size_t)JH_ * EH_ * 2);
  u16* WpredB = (u16*)alloc((size_t)JH_ * PH_ * 2);
  u16* Wpk    = (u16*)alloc((size_t)KT_ * 32768 * 2);
  float* eBuf = (float*)alloc((size_t)B_ * T_ * JH_ * 4);
  float* pBuf = (float*)alloc((size_t)B_ * U_ * JH_ * 4);
  float* pPk  = (float*)alloc((size_t)81920 * 4 * 4);

  // front-end
  k_transpose_cvt<<<dim3(T_ / 32, EH_ / 32, B_), 256, 0, stream>>>(enc, encT, EH_, T_);
  k_transpose_cvt<<<dim3(U_ / 32, PH_ / 32, B_), 256, 0, stream>>>(dec, decT, PH_, U_);
  k_prep_w<<<1360, 256, 0, stream>>>(W_enc, W_pred, W_out, WencB, WpredB, Wpk);
  k_proj_gemm<<<dim3(T_ / 64, JH_ / 64, B_), 256, 0, stream>>>(
      encT, WencB, b_enc, eBuf, EH_, JH_, (size_t)T_ * EH_, (size_t)T_ * JH_);
  k_proj_gemm<<<dim3(U_ / 64, JH_ / 64, B_), 256, 0, stream>>>(
      decT, WpredB, b_pred, pBuf, PH_, JH_, (size_t)U_ * PH_, (size_t)U_ * JH_);
  k_pack_p2<<<320, 256, 0, stream>>>(pBuf, pPk);

  // fused joint GEMM + log_softmax: one block per 64 output rows
  k_fused4<<<B_ * T_ * 2, 512, 0, stream>>>(eBuf, pPk, Wpk, b_out, out);
}